// Round 11
// baseline (1885.365 us; speedup 1.0000x reference)
//
#include <hip/hip_runtime.h>
#include <stdint.h>

typedef __fp16 half2v __attribute__((ext_vector_type(2)));
typedef __fp16 half8v __attribute__((ext_vector_type(8)));
typedef float floatx4 __attribute__((ext_vector_type(4)));

#define Lr   512
#define Br   128
#define DINr 256
#define DHr  512

__device__ __forceinline__ float fdot2(half2v a, half2v b, float c) {
    return __builtin_amdgcn_fdot2(a, b, c, false);
}
__device__ __forceinline__ uint32_t pk_u32(float lo, float hi) {
    half2v h = __builtin_amdgcn_cvt_pkrtz(lo, hi);
    return __builtin_bit_cast(uint32_t, h);
}
__device__ __forceinline__ half2v u32_h2(uint32_t u) {
    return __builtin_bit_cast(half2v, u);
}

// ---------------------------------------------------------------------------
// Kernel W: convert Wx (f32 [256][512]) into MFMA-B-fragment-ordered f16.
// ---------------------------------------------------------------------------
__global__ __launch_bounds__(512)
void wxcvt_kernel(const float* __restrict__ Wx, __fp16* __restrict__ bt)
{
    const int gid = blockIdx.x * 512 + threadIdx.x;   // 256 blocks -> 131072
    const int k = gid >> 9;
    const int n = gid & 511;
    const int s = k >> 5, g = (k >> 3) & 3, j = k & 7;
    const int nt = n >> 4, r = n & 15;
    const int idx = ((((nt * 8 + s) * 4 + g) * 16 + r) * 8) + j;
    bt[idx] = (__fp16)Wx[gid];
}

// ---------------------------------------------------------------------------
// Kernel A: xp = x @ Wx + bx via f16 MFMA 16x16x32 (verified round 9).
// ---------------------------------------------------------------------------
__global__ __launch_bounds__(512)
void xp_mfma_kernel(const float* __restrict__ x, const __fp16* __restrict__ bt,
                    const float* __restrict__ bx, float* __restrict__ out)
{
    const int tid  = threadIdx.x;
    const int w    = tid >> 6;
    const int lane = tid & 63;
    const int g    = lane >> 4;
    const int r    = lane & 15;
    const int m0   = blockIdx.x * 128 + w * 16;

    const float* xrow = x + (size_t)(m0 + r) * DINr;
    half8v af[8];
    #pragma unroll
    for (int s = 0; s < 8; ++s) {
        const float4 u = *(const float4*)(xrow + 32 * s + 8 * g);
        const float4 v = *(const float4*)(xrow + 32 * s + 8 * g + 4);
        half8v a;
        a[0] = (__fp16)u.x; a[1] = (__fp16)u.y; a[2] = (__fp16)u.z; a[3] = (__fp16)u.w;
        a[4] = (__fp16)v.x; a[5] = (__fp16)v.y; a[6] = (__fp16)v.z; a[7] = (__fp16)v.w;
        af[s] = a;
    }

    const half8v* bt8 = (const half8v*)bt;

    #pragma unroll 4
    for (int nt = 0; nt < 32; ++nt) {
        floatx4 acc = {0.f, 0.f, 0.f, 0.f};
        #pragma unroll
        for (int s = 0; s < 8; ++s) {
            const half8v bf = bt8[((nt * 8 + s) * 4 + g) * 16 + r];
            acc = __builtin_amdgcn_mfma_f32_16x16x32_f16(af[s], bf, acc, 0, 0, 0);
        }
        const float bxv = bx[nt * 16 + r];
        #pragma unroll
        for (int q = 0; q < 4; ++q) {
            out[(size_t)(m0 + 4 * g + q) * DHr + nt * 16 + r] = acc[q] + bxv;
        }
    }
}

// ---------------------------------------------------------------------------
// Kernel B: persistent recurrence (round-9 structure, all weights in regs).
// 128 blocks x 512 threads, 1 block/CU. Thread (wave w, lane l): owns cols
// {p, p+256}, p = w*32 + (l&31); k-half s = l>>5 (128 pairs per col).
// ALL 128 pairs/col live in register arrays (-> VGPR+AGPR, ~512-reg budget
// at 2 waves/SIMD; __launch_bounds__(512,1)). NO LDS weight arrays: the LDS
// pipe carries only 32 h-broadcast b128 reads + 1 hbuf write per step.
// k-halves reduced with shfl_xor(32); one __syncthreads per step.
// ---------------------------------------------------------------------------
__global__ __launch_bounds__(512, 1)
void rnn_kernel(const float* __restrict__ h0, const float* __restrict__ Wh,
                const float* __restrict__ bh, float* __restrict__ out)
{
    const int tid   = threadIdx.x;
    const int b     = blockIdx.x;
    const int lane  = tid & 63;
    const int wv    = tid >> 6;
    const int p     = wv * 32 + (lane & 31);
    const int s     = lane >> 5;                  // k-half
    const int mycol = (lane < 32) ? p : (p + 256);

    __shared__ __align__(16) uint32_t hbuf[2][256];   // packed h pairs

    half2v wr0[128], wr1[128];
    #pragma unroll
    for (int q = 0; q < 128; ++q) {
        const int k = 2 * (s * 128 + q);
        const float* Wk  = Wh + (size_t)k * DHr;
        const float* Wk1 = Wk + DHr;
        wr0[q] = __builtin_amdgcn_cvt_pkrtz(Wk[p],       Wk1[p]);
        wr1[q] = __builtin_amdgcn_cvt_pkrtz(Wk[p + 256], Wk1[p + 256]);
    }
    const float bhv = bh[mycol];
    float xpv = out[(size_t)b * DHr + mycol];     // xp for t=0 (from kernel A)

    if (tid < 256) {
        const float* h0b = h0 + (size_t)b * DHr + 2 * tid;
        hbuf[0][tid] = pk_u32(h0b[0], h0b[1]);
    }
    __syncthreads();

    #pragma unroll 1
    for (int t = 0; t < Lr; ++t) {
        const uint32_t* hb = &hbuf[t & 1][s * 128];
        float ac00 = 0.f, ac01 = 0.f, ac10 = 0.f, ac11 = 0.f;
        #pragma unroll
        for (int c = 0; c < 32; ++c) {            // all 128 pairs from regs
            const uint4 hv = *(const uint4*)&hb[c * 4];
            ac00 = fdot2(u32_h2(hv.x), wr0[4*c+0], ac00);
            ac10 = fdot2(u32_h2(hv.x), wr1[4*c+0], ac10);
            ac01 = fdot2(u32_h2(hv.y), wr0[4*c+1], ac01);
            ac11 = fdot2(u32_h2(hv.y), wr1[4*c+1], ac11);
            ac00 = fdot2(u32_h2(hv.z), wr0[4*c+2], ac00);
            ac10 = fdot2(u32_h2(hv.z), wr1[4*c+2], ac10);
            ac01 = fdot2(u32_h2(hv.w), wr0[4*c+3], ac01);
            ac11 = fdot2(u32_h2(hv.w), wr1[4*c+3], ac11);
        }
        const float sA = ac00 + ac01;
        const float sB = ac10 + ac11;
        const float rA = sA + __shfl_xor(sA, 32, 64);
        const float rB = sB + __shfl_xor(sB, 32, 64);
        const float sum = (lane < 32) ? rA : rB;

        const float svv = sum + xpv + bhv;
        const float e   = __expf(2.f * svv);
        const float h   = 1.f - 2.f * __builtin_amdgcn_rcpf(e + 1.f);

        out[(size_t)(t * Br + b) * DHr + mycol] = h;
        if (t + 1 < Lr)
            xpv = out[(size_t)((t + 1) * Br + b) * DHr + mycol];  // prefetch xp

        const float hx = __shfl_xor(h, 1, 64);
        if (!(lane & 1))
            hbuf[(t + 1) & 1][mycol >> 1] = pk_u32(h, hx);
        __syncthreads();
    }
}

extern "C" void kernel_launch(void* const* d_in, const int* in_sizes, int n_in,
                              void* d_out, int out_size, void* d_ws, size_t ws_size,
                              hipStream_t stream) {
    (void)in_sizes; (void)n_in; (void)ws_size; (void)out_size;
    const float* x  = (const float*)d_in[0];
    const float* h0 = (const float*)d_in[1];
    const float* Wx = (const float*)d_in[2];
    const float* bx = (const float*)d_in[3];
    const float* Wh = (const float*)d_in[4];
    const float* bh = (const float*)d_in[5];
    float* out  = (float*)d_out;
    __fp16* bt  = (__fp16*)d_ws;   // 131072 * 2B = 256 KB of workspace

    wxcvt_kernel<<<dim3(256), dim3(512), 0, stream>>>(Wx, bt);
    xp_mfma_kernel<<<dim3(512), dim3(512), 0, stream>>>(x, bt, bx, out);
    rnn_kernel<<<dim3(128), dim3(512), 0, stream>>>(h0, Wh, bh, out);
}

// Round 15
// 1180.267 us; speedup vs baseline: 1.5974x; 1.5974x over previous
//
#include <hip/hip_runtime.h>
#include <stdint.h>

typedef __fp16 half2v __attribute__((ext_vector_type(2)));
typedef __fp16 half8v __attribute__((ext_vector_type(8)));
typedef float floatx4 __attribute__((ext_vector_type(4)));

#define Lr   512
#define Br   128
#define DINr 256
#define DHr  512

__device__ __forceinline__ float fdot2(half2v a, half2v b, float c) {
    return __builtin_amdgcn_fdot2(a, b, c, false);
}
__device__ __forceinline__ uint32_t pk_u32(float lo, float hi) {
    half2v h = __builtin_amdgcn_cvt_pkrtz(lo, hi);
    return __builtin_bit_cast(uint32_t, h);
}
__device__ __forceinline__ half2v u32_h2(uint32_t u) {
    return __builtin_bit_cast(half2v, u);
}

// ---------------------------------------------------------------------------
// Kernel W: convert Wx (f32 [256][512]) into MFMA-B-fragment-ordered f16.
// ---------------------------------------------------------------------------
__global__ __launch_bounds__(512)
void wxcvt_kernel(const float* __restrict__ Wx, __fp16* __restrict__ bt)
{
    const int gid = blockIdx.x * 512 + threadIdx.x;   // 256 blocks -> 131072
    const int k = gid >> 9;
    const int n = gid & 511;
    const int s = k >> 5, g = (k >> 3) & 3, j = k & 7;
    const int nt = n >> 4, r = n & 15;
    const int idx = ((((nt * 8 + s) * 4 + g) * 16 + r) * 8) + j;
    bt[idx] = (__fp16)Wx[gid];
}

// ---------------------------------------------------------------------------
// Kernel A: xp = x @ Wx + bx via f16 MFMA 16x16x32 (verified round 9).
// ---------------------------------------------------------------------------
__global__ __launch_bounds__(512)
void xp_mfma_kernel(const float* __restrict__ x, const __fp16* __restrict__ bt,
                    const float* __restrict__ bx, float* __restrict__ out)
{
    const int tid  = threadIdx.x;
    const int w    = tid >> 6;
    const int lane = tid & 63;
    const int g    = lane >> 4;
    const int r    = lane & 15;
    const int m0   = blockIdx.x * 128 + w * 16;

    const float* xrow = x + (size_t)(m0 + r) * DINr;
    half8v af[8];
    #pragma unroll
    for (int s = 0; s < 8; ++s) {
        const float4 u = *(const float4*)(xrow + 32 * s + 8 * g);
        const float4 v = *(const float4*)(xrow + 32 * s + 8 * g + 4);
        half8v a;
        a[0] = (__fp16)u.x; a[1] = (__fp16)u.y; a[2] = (__fp16)u.z; a[3] = (__fp16)u.w;
        a[4] = (__fp16)v.x; a[5] = (__fp16)v.y; a[6] = (__fp16)v.z; a[7] = (__fp16)v.w;
        af[s] = a;
    }

    const half8v* bt8 = (const half8v*)bt;

    #pragma unroll 4
    for (int nt = 0; nt < 32; ++nt) {
        floatx4 acc = {0.f, 0.f, 0.f, 0.f};
        #pragma unroll
        for (int s = 0; s < 8; ++s) {
            const half8v bf = bt8[((nt * 8 + s) * 4 + g) * 16 + r];
            acc = __builtin_amdgcn_mfma_f32_16x16x32_f16(af[s], bf, acc, 0, 0, 0);
        }
        const float bxv = bx[nt * 16 + r];
        #pragma unroll
        for (int q = 0; q < 4; ++q) {
            out[(size_t)(m0 + 4 * g + q) * DHr + nt * 16 + r] = acc[q] + bxv;
        }
    }
}

// ---------------------------------------------------------------------------
// Kernel B: persistent recurrence, 1024 thr/block (16 waves, 4/SIMD for
// latency hiding; reg budget 128/lane). Wave wv: kh = wv&1 (k-half),
// cg = wv>>1; lane owns ONE column c = cg*64+lane, 128 k-pairs of half kh:
// 92 pairs in regs + 36 pairs in LDS ([9][1024] uint4, b128 reads, 144 KB).
// Cross-k-half reduce via part[] LDS exchange; kh=0 waves finish (tanh,
// global store, hbuf pack). h broadcast: 32 uniform b128 reads/wave.
// Two __syncthreads per step.
// ---------------------------------------------------------------------------
__global__ __launch_bounds__(1024, 1)
void rnn_kernel(const float* __restrict__ h0, const float* __restrict__ Wh,
                const float* __restrict__ bh, float* __restrict__ out)
{
    const int tid  = threadIdx.x;
    const int b    = blockIdx.x;
    const int lane = tid & 63;
    const int wv   = tid >> 6;            // 0..15
    const int kh   = wv & 1;              // k-half
    const int cg   = wv >> 1;             // 0..7
    const int c    = cg * 64 + lane;      // column 0..511

    __shared__ __align__(16) uint32_t hbuf[2][256];   // packed h pairs
    __shared__ float part[512];                       // kh=1 partials
    __shared__ __align__(16) uint4 wlds[9][1024];     // pairs 92..127

    half2v wr[92];
    #pragma unroll
    for (int q = 0; q < 92; ++q) {
        const int k = 2 * (kh * 128 + q);
        wr[q] = __builtin_amdgcn_cvt_pkrtz(Wh[(size_t)k * DHr + c],
                                           Wh[(size_t)(k + 1) * DHr + c]);
    }
    #pragma unroll
    for (int c4 = 0; c4 < 9; ++c4) {
        uint4 qa;
        uint32_t* qw = (uint32_t*)&qa;
        #pragma unroll
        for (int j = 0; j < 4; ++j) {
            const int q = 92 + 4 * c4 + j;
            const int k = 2 * (kh * 128 + q);
            qw[j] = pk_u32(Wh[(size_t)k * DHr + c], Wh[(size_t)(k + 1) * DHr + c]);
        }
        wlds[c4][tid] = qa;
    }

    const float bhv = bh[c];
    float xpv = (kh == 0) ? out[(size_t)b * DHr + c] : 0.f;  // xp for t=0

    if (tid < 256) {
        const float* h0b = h0 + (size_t)b * DHr + 2 * tid;
        hbuf[0][tid] = pk_u32(h0b[0], h0b[1]);
    }
    __syncthreads();

    #pragma unroll 1
    for (int t = 0; t < Lr; ++t) {
        const uint32_t* hb = &hbuf[t & 1][kh * 128];
        float a0 = 0.f, a1 = 0.f, a2 = 0.f, a3 = 0.f;
        #pragma unroll
        for (int m = 0; m < 23; ++m) {        // pairs 0..91 (register weights)
            const uint4 hv = *(const uint4*)&hb[m * 4];
            a0 = fdot2(u32_h2(hv.x), wr[4*m+0], a0);
            a1 = fdot2(u32_h2(hv.y), wr[4*m+1], a1);
            a2 = fdot2(u32_h2(hv.z), wr[4*m+2], a2);
            a3 = fdot2(u32_h2(hv.w), wr[4*m+3], a3);
        }
        #pragma unroll
        for (int c4 = 0; c4 < 9; ++c4) {      // pairs 92..127 (LDS weights)
            const uint4 hv = *(const uint4*)&hb[92 + c4 * 4];
            const uint4 w  = wlds[c4][tid];
            a0 = fdot2(u32_h2(hv.x), u32_h2(w.x), a0);
            a1 = fdot2(u32_h2(hv.y), u32_h2(w.y), a1);
            a2 = fdot2(u32_h2(hv.z), u32_h2(w.z), a2);
            a3 = fdot2(u32_h2(hv.w), u32_h2(w.w), a3);
        }
        const float sown = (a0 + a1) + (a2 + a3);

        if (kh) part[c] = sown;
        __syncthreads();                      // barrier 1

        if (!kh) {
            const float o = sown + part[c] + xpv + bhv;
            const float e = __expf(2.f * o);
            const float h = 1.f - 2.f * __builtin_amdgcn_rcpf(e + 1.f);

            out[(size_t)(t * Br + b) * DHr + c] = h;
            if (t + 1 < Lr)
                xpv = out[(size_t)((t + 1) * Br + b) * DHr + c];  // prefetch xp

            const float hx = __shfl_xor(h, 1, 64);
            if (!(lane & 1))
                hbuf[(t + 1) & 1][c >> 1] = pk_u32(h, hx);
        }
        __syncthreads();                      // barrier 2
    }
}

extern "C" void kernel_launch(void* const* d_in, const int* in_sizes, int n_in,
                              void* d_out, int out_size, void* d_ws, size_t ws_size,
                              hipStream_t stream) {
    (void)in_sizes; (void)n_in; (void)ws_size; (void)out_size;
    const float* x  = (const float*)d_in[0];
    const float* h0 = (const float*)d_in[1];
    const float* Wx = (const float*)d_in[2];
    const float* bx = (const float*)d_in[3];
    const float* Wh = (const float*)d_in[4];
    const float* bh = (const float*)d_in[5];
    float* out  = (float*)d_out;
    __fp16* bt  = (__fp16*)d_ws;   // 131072 * 2B = 256 KB of workspace

    wxcvt_kernel<<<dim3(256), dim3(512), 0, stream>>>(Wx, bt);
    xp_mfma_kernel<<<dim3(512), dim3(512), 0, stream>>>(x, bt, bx, out);
    rnn_kernel<<<dim3(128), dim3(1024), 0, stream>>>(h0, Wh, bh, out);
}